// Round 15
// baseline (591.506 us; speedup 1.0000x reference)
//
#include <hip/hip_runtime.h>
#include <hip/hip_bf16.h>

typedef unsigned short u16;
typedef unsigned int u32;
typedef unsigned long long u64;
typedef __attribute__((ext_vector_type(8))) short short8;
typedef __attribute__((ext_vector_type(4))) float floatx4;

#define MFMA16(a,b,c) __builtin_amdgcn_mfma_f32_16x16x32_bf16((a),(b),(c),0,0,0)

__device__ __forceinline__ u16 f2bf(float f){
  u32 x = __float_as_uint(f);
  x += 0x7FFFu + ((x >> 16) & 1u);
  return (u16)(x >> 16);
}
__device__ __forceinline__ float frcp(float x){ return __builtin_amdgcn_rcpf(x); }
__device__ __forceinline__ float fexp2(float x){ return __builtin_amdgcn_exp2f(x); }
// 0.125 * log2(e): scale folded into the exp2 argument
#define KEXP 0.18033688011112042f
#define Z4 ((floatx4){0.f,0.f,0.f,0.f})

// async global->LDS 16B per lane: LDS dest = wave-uniform base + lane*16,
// global src is per-lane (pre-swizzled source pattern).
__device__ __forceinline__ void gl_lds16(const u16* src, u16* dst){
  __builtin_amdgcn_global_load_lds(
      (const __attribute__((address_space(1))) unsigned int*)(u64)(src),
      (__attribute__((address_space(3))) unsigned int*)(u32)(u64)(dst),
      16, 0, 0);
}

// P-buffer swizzle (mono fallback): 16-elem (32B) windows XORed by (row>>2)&3.
__device__ __forceinline__ int p_idx(int row, int col){
  return row * 1024 + (col ^ (((row >> 2) & 3) << 4));
}

// ---------------- weight transpose+convert (all 6): wt[z][j][d] = bf16(w[z][d][j]) ----
__global__ __launch_bounds__(256) void k_wt6(
    const float* __restrict__ w0, const float* __restrict__ w1, const float* __restrict__ w2,
    const float* __restrict__ w3, const float* __restrict__ w4, const float* __restrict__ w5,
    u16* __restrict__ wts)
{
  int z = blockIdx.y;
  const float* w;
  switch (z){ case 0: w = w0; break; case 1: w = w1; break; case 2: w = w2; break;
              case 3: w = w3; break; case 4: w = w4; break; default: w = w5; break; }
  int idx = blockIdx.x * 256 + threadIdx.x;
  int j = idx >> 9, d = idx & 511;
  wts[(size_t)z * 262144 + idx] = f2bf(w[d * 512 + j]);
}

// ---------------- 5-way projection GEMM, 128x128 tile (R14-proven) ----------------
__global__ __launch_bounds__(256) void k_proj(
    const float* __restrict__ xq, const float* __restrict__ xk, const float* __restrict__ xv,
    const u16* __restrict__ wts,
    const float* __restrict__ bq, const float* __restrict__ bk, const float* __restrict__ bv,
    const float* __restrict__ bq1, const float* __restrict__ bk1,
    u16* __restrict__ Qh, u16* __restrict__ Kh, u16* __restrict__ Vt,
    u16* __restrict__ Q1h, u16* __restrict__ K1h)
{
  __shared__ __align__(16) u16 As[128][72];
  __shared__ __align__(16) u16 Bs[128 * 64];
  int z = blockIdx.z;
  const float* x; const float* bias; u16* out; int vtm = 0;
  switch (z){
    case 0: x = xq; bias = bq;  out = Qh;  break;
    case 1: x = xk; bias = bk;  out = Kh;  break;
    case 2: x = xv; bias = bv;  out = Vt;  vtm = 1; break;
    case 3: x = xq; bias = bq1; out = Q1h; break;
    default: x = xk; bias = bk1; out = K1h; break;
  }
  const u16* wt = wts + (size_t)z * 262144;
  const int tid = threadIdx.x, lane = tid & 63, wid = tid >> 6;
  const int wm = wid >> 1, wn = wid & 1;
  const int m0 = blockIdx.x * 128, n0 = blockIdx.y * 128;
  const int arow = lane & 15, kg = lane >> 4;
  const int ar = tid >> 1, ah = (tid & 1) * 32;
  const int br = tid >> 3, bc = tid & 7;
  u16* const bdst = Bs + wid * 512;

  floatx4 acc[4][4];
  #pragma unroll
  for (int i = 0; i < 4; ++i)
    #pragma unroll
    for (int j = 0; j < 4; ++j) acc[i][j] = Z4;

  for (int k0 = 0; k0 < 512; k0 += 64){
    #pragma unroll
    for (int q = 0; q < 4; ++q)
      gl_lds16(wt + (size_t)(n0 + q * 32 + br) * 512 + k0 + ((bc ^ (br & 7)) * 8),
               bdst + q * 2048);
    const float4* xp = (const float4*)(x + (size_t)(m0 + ar) * 512 + k0 + ah);
    #pragma unroll
    for (int j = 0; j < 4; ++j){
      float4 f0 = xp[2 * j], f1 = xp[2 * j + 1];
      short8 v;
      v[0] = (short)f2bf(f0.x); v[1] = (short)f2bf(f0.y);
      v[2] = (short)f2bf(f0.z); v[3] = (short)f2bf(f0.w);
      v[4] = (short)f2bf(f1.x); v[5] = (short)f2bf(f1.y);
      v[6] = (short)f2bf(f1.z); v[7] = (short)f2bf(f1.w);
      *(short8*)&As[ar][ah + j * 8] = v;
    }
    __syncthreads();
    #pragma unroll
    for (int kk = 0; kk < 2; ++kk){
      short8 af[4], bf[4];
      #pragma unroll
      for (int mm = 0; mm < 4; ++mm)
        af[mm] = *(const short8*)&As[wm * 64 + mm * 16 + arow][kk * 32 + kg * 8];
      #pragma unroll
      for (int nn = 0; nn < 4; ++nn){
        int rr = wn * 64 + nn * 16 + arow;
        bf[nn] = *(const short8*)&Bs[rr * 64 + ((kk * 32 + kg * 8) ^ ((rr & 7) * 8))];
      }
      #pragma unroll
      for (int mm = 0; mm < 4; ++mm)
        #pragma unroll
        for (int nn = 0; nn < 4; ++nn)
          acc[mm][nn] = MFMA16(af[mm], bf[nn], acc[mm][nn]);
    }
    __syncthreads();
  }
  #pragma unroll
  for (int mm = 0; mm < 4; ++mm)
    #pragma unroll
    for (int nn = 0; nn < 4; ++nn){
      int j = n0 + wn * 64 + nn * 16 + arow;
      int h = j >> 6, dh = j & 63;
      float bval = bias[j];
      #pragma unroll
      for (int i = 0; i < 4; ++i){
        int sg = m0 + wm * 64 + mm * 16 + kg * 4 + i;
        int bb = sg >> 10, s = sg & 1023;
        float val = acc[mm][nn][i] + bval;
        size_t o = vtm ? (((size_t)((bb << 3) + h) * 64 + dh) * 1024 + s)
                       : (((size_t)((bb << 3) + h) * 1024 + s) * 64 + dh);
        out[o] = f2bf(val);
      }
    }
}

// ================= SPLIT PATH =================
// ---------------- kernel A: dual-QK logits -> u = exp*sigmoid -> U, rsum -------------
// grid (16 b, 16 qt, 8 h) = 2048 blocks; 1024 thr; 33 KB LDS -> 2 blocks/CU.
// R6's proven QK phase minus P/ratt/PV: u goes straight to global U (bf16).
__global__ void __launch_bounds__(1024)
k_qk(const u16* __restrict__ Qh, const u16* __restrict__ Kh,
     const u16* __restrict__ Q1h, const u16* __restrict__ K1h,
     const int* __restrict__ mask, u16* __restrict__ U, float* __restrict__ rsum)
{
  __shared__ __align__(16) u16 stg[2 * 8192];
  __shared__ float ssum[64 * 4];

  const int tid = threadIdx.x, lane = tid & 63, wid = tid >> 6;
  const int arow = lane & 15, kg = lane >> 4;
  const int b = blockIdx.x, qt = blockIdx.y, h = blockIdx.z;
  const int r0 = (wid & 3) * 16;
  const int cres = ((wid >> 2) * 16) + arow;

  const int ls_half = tid >> 9;
  const int ls_r = (tid & 511) >> 3;
  const int ls_c = (tid & 7) ^ (ls_r & 7);
  u16* const sbase = stg + wid * 512;

  u32 mb = 0;
  #pragma unroll
  for (int t = 0; t < 16; ++t)
    mb |= (mask[b * 1024 + t * 64 + cres] != 0 ? 1u : 0u) << t;

  const size_t hb = (size_t)(b * 8 + h);
  const u16* qp  = Qh  + (hb * 1024 + qt * 64 + r0 + arow) * 64 + kg * 8;
  const u16* q1p = Q1h + (hb * 1024 + qt * 64 + r0 + arow) * 64 + kg * 8;
  short8 aq0 = *(const short8*)qp,  aq1 = *(const short8*)(qp + 32);
  short8 ap0 = *(const short8*)q1p, ap1 = *(const short8*)(q1p + 32);

  const u16* lsrc = (ls_half ? Kh : K1h) + hb * 65536 + (size_t)ls_r * 64 + ls_c * 8;
  u16* const ubase = U + hb * 1048576;

  gl_lds16(lsrc, sbase);
  __syncthreads();

  float sacc[4] = {0.f, 0.f, 0.f, 0.f};
  for (int t = 0; t < 16; ++t){
    if (t < 15)
      gl_lds16(lsrc + (size_t)(t + 1) * 4096, sbase + (((t + 1) & 1) << 13));
    const u16* kb = stg + ((t & 1) << 13);
    const int swl = (cres & 7) * 8;
    short8 b1a = *(const short8*)&kb[cres * 64 + ((     kg * 8) ^ swl)];
    short8 b1b = *(const short8*)&kb[cres * 64 + ((32 + kg * 8) ^ swl)];
    short8 bea = *(const short8*)&kb[4096 + cres * 64 + ((     kg * 8) ^ swl)];
    short8 beb = *(const short8*)&kb[4096 + cres * 64 + ((32 + kg * 8) ^ swl)];
    floatx4 cg = Z4, ce = Z4;
    cg = MFMA16(ap0, b1a, cg); cg = MFMA16(ap1, b1b, cg);
    ce = MFMA16(aq0, bea, ce); ce = MFMA16(aq1, beb, ce);
    const float msk = ((mb >> t) & 1u) ? 1.0f : 0.0f;
    #pragma unroll
    for (int i = 0; i < 4; ++i){
      float p = fexp2(ce[i] * KEXP) * msk;
      float g = frcp(1.0f + fexp2(-cg[i] * KEXP));
      sacc[i] += p;
      ubase[(size_t)(qt * 64 + r0 + kg * 4 + i) * 1024 + t * 64 + cres] = f2bf(p * g);
    }
    __syncthreads();
  }

  #pragma unroll
  for (int i = 0; i < 4; ++i){
    #pragma unroll
    for (int off = 1; off <= 8; off <<= 1)
      sacc[i] += __shfl_xor(sacc[i], off, 64);
  }
  if (arow == 0){
    #pragma unroll
    for (int i = 0; i < 4; ++i)
      ssum[(r0 + kg * 4 + i) * 4 + (wid >> 2)] = sacc[i];
  }
  __syncthreads();
  if (tid < 64){
    float s = ssum[tid * 4 + 0] + ssum[tid * 4 + 1] + ssum[tid * 4 + 2] + ssum[tid * 4 + 3];
    rsum[hb * 1024 + qt * 64 + tid] = s;
  }
}

// ---------------- kernel B: r_att accumulation + PV from U -------------
// grid (16 b, 32 qt); 512 thr (8 waves); 32 KB LDS -> 2 blocks/CU; loops 8 heads.
// racc phase: barrier-free coalesced U reads, rl from rsum. PV: A-frags direct from
// L2-hot U, V staged (R12-proven maps). 9 barriers/head (vs mono's 28).
__global__ void __launch_bounds__(512)
__attribute__((amdgpu_waves_per_eu(4, 4)))
k_pvr(const u16* __restrict__ U, const float* __restrict__ rsum,
      const u16* __restrict__ Vt, u16* __restrict__ xa, float* __restrict__ ratt)
{
  __shared__ __align__(16) u16 stg[2 * 8192];

  const int tid = threadIdx.x, lane = tid & 63, wid = tid >> 6;
  const int arow = lane & 15, kg = lane >> 4;
  const int b = blockIdx.x, qt = blockIdx.y;
  const int s2 = wid & 1, cg = wid >> 1;
  const int cres = cg * 16 + arow;          // dh residue
  const int wrow = wid * 4;

  const int pv_r0 = tid >> 4;
  const int pv_c0 = (tid & 15) ^ (pv_r0 & 7);
  const int pv_r1 = pv_r0 + 32;
  const int pv_c1 = (tid & 15) ^ (pv_r1 & 7);
  u16* const sbase = stg + wid * 512;

  float racc[4][16];
  #pragma unroll
  for (int r = 0; r < 4; ++r)
    #pragma unroll
    for (int j = 0; j < 16; ++j) racc[r][j] = 0.f;

  for (int h = 0; h < 8; ++h){
    const size_t hb = (size_t)(b * 8 + h);
    const u16* ub = U + hb * 1048576;

    // ---- racc accumulation (barrier-free, coalesced) ----
    #pragma unroll
    for (int r = 0; r < 4; ++r){
      const int g = qt * 32 + wrow + r;
      float rlh = frcp(rsum[hb * 1024 + g]) * 0.125f;
      #pragma unroll
      for (int j = 0; j < 8; ++j){
        u32 w = *(const u32*)&ub[(size_t)g * 1024 + j * 128 + lane * 2];
        racc[r][2 * j]     += __uint_as_float(w << 16) * rlh;
        racc[r][2 * j + 1] += __uint_as_float(w & 0xFFFF0000u) * rlh;
      }
    }

    // ---- PV: V staged (dbuf), A-frags from L2-hot U ----
    const u16* vs0 = Vt + hb * 65536 + (size_t)pv_r0 * 1024 + pv_c0 * 8;
    const u16* vs1 = Vt + hb * 65536 + (size_t)pv_r1 * 1024 + pv_c1 * 8;
    gl_lds16(vs0, sbase);
    gl_lds16(vs1, sbase + 4096);
    __syncthreads();

    const u16* ab = ub + (size_t)(qt * 32 + s2 * 16 + arow) * 1024;
    floatx4 cpv = Z4;
    for (int t = 0; t < 8; ++t){
      if (t < 7){
        gl_lds16(vs0 + (size_t)(t + 1) * 128, sbase + (((t + 1) & 1) << 13));
        gl_lds16(vs1 + (size_t)(t + 1) * 128, sbase + 4096 + (((t + 1) & 1) << 13));
      }
      const u16* vb = stg + ((t & 1) << 13);
      const int swv = (cres & 7) * 8;
      #pragma unroll
      for (int ks = 0; ks < 4; ++ks){
        short8 a  = *(const short8*)&ab[t * 128 + ks * 32 + kg * 8];
        short8 bv = *(const short8*)&vb[cres * 128 + ((ks * 32 + kg * 8) ^ swv)];
        cpv = MFMA16(a, bv, cpv);
      }
      __syncthreads();
    }
    // ---- epilogue: scale by 1/sum, write xa ----
    #pragma unroll
    for (int i = 0; i < 4; ++i){
      const int g = qt * 32 + s2 * 16 + kg * 4 + i;
      float rl = frcp(rsum[hb * 1024 + g]);
      xa[((size_t)(b * 1024 + g)) * 512 + h * 64 + cres] = f2bf(cpv[i] * rl);
    }
  }

  // ---- r_att writeout (float2-coalesced: col = j*128 + lane*2 + par) ----
  #pragma unroll
  for (int r = 0; r < 4; ++r){
    const size_t rb = ((size_t)(b * 1024 + qt * 32 + wrow + r)) * 1024;
    #pragma unroll
    for (int j = 0; j < 8; ++j){
      float2 v = {racc[r][2 * j], racc[r][2 * j + 1]};
      *(float2*)&ratt[rb + j * 128 + lane * 2] = v;
    }
  }
}

// ================= MONO FALLBACK (R6/R14-proven, 362 us) =================
__global__ void __launch_bounds__(1024)
__attribute__((amdgpu_waves_per_eu(4, 4)))
k_attn(
    const u16* __restrict__ Qh, const u16* __restrict__ Kh, const u16* __restrict__ Vt,
    const u16* __restrict__ Q1h, const u16* __restrict__ K1h,
    const int* __restrict__ mask, u16* __restrict__ xa, float* __restrict__ ratt)
{
  extern __shared__ __align__(16) char smem[];
  u16* P   = (u16*)smem;
  u16* stg = (u16*)(smem + 131072);
  float* ssum = (float*)(smem + 131072);
  float* rls  = (float*)(smem + 131072 + 1024);

  const int tid = threadIdx.x, lane = tid & 63, wid = tid >> 6;
  const int arow = lane & 15, kg = lane >> 4;
  const int b = blockIdx.x, qt = blockIdx.y;
  const int r0 = (wid & 3) * 16;
  const int cres = ((wid >> 2) * 16) + arow;
  const int wrow = wid * 4;

  const int ls_half = tid >> 9;
  const int ls_r = (tid & 511) >> 3;
  const int ls_c = (tid & 7) ^ (ls_r & 7);
  const int pv_r = tid >> 4;
  const int pv_c = (tid & 15) ^ (pv_r & 7);
  u16* const sbase = stg + wid * 512;

  u32 mb = 0;
  #pragma unroll
  for (int t = 0; t < 16; ++t)
    mb |= (mask[b * 1024 + t * 64 + cres] != 0 ? 1u : 0u) << t;

  float racc[4][16];
  #pragma unroll
  for (int r = 0; r < 4; ++r)
    #pragma unroll
    for (int j = 0; j < 16; ++j) racc[r][j] = 0.f;

  for (int h = 0; h < 8; ++h){
    const size_t hb = (size_t)(b * 8 + h);
    const u16* qp  = Qh  + (hb * 1024 + qt * 64 + r0 + arow) * 64 + kg * 8;
    const u16* q1p = Q1h + (hb * 1024 + qt * 64 + r0 + arow) * 64 + kg * 8;
    short8 aq0 = *(const short8*)qp,  aq1 = *(const short8*)(qp + 32);
    short8 ap0 = *(const short8*)q1p, ap1 = *(const short8*)(q1p + 32);

    const u16* lsrc = (ls_half ? Kh : K1h) + hb * 65536 + (size_t)ls_r * 64 + ls_c * 8;

    gl_lds16(lsrc, sbase);
    __syncthreads();

    float sacc[4] = {0.f, 0.f, 0.f, 0.f};
    for (int t = 0; t < 16; ++t){
      if (t < 15)
        gl_lds16(lsrc + (size_t)(t + 1) * 4096, sbase + (((t + 1) & 1) << 13));
      const u16* kb = stg + ((t & 1) << 13);
      const int swl = (cres & 7) * 8;
      short8 b1a = *(const short8*)&kb[cres * 64 + ((     kg * 8) ^ swl)];
      short8 b1b = *(const short8*)&kb[cres * 64 + ((32 + kg * 8) ^ swl)];
      short8 bea = *(const short8*)&kb[4096 + cres * 64 + ((     kg * 8) ^ swl)];
      short8 beb = *(const short8*)&kb[4096 + cres * 64 + ((32 + kg * 8) ^ swl)];
      floatx4 cg = Z4, ce = Z4;
      cg = MFMA16(ap0, b1a, cg); cg = MFMA16(ap1, b1b, cg);
      ce = MFMA16(aq0, bea, ce); ce = MFMA16(aq1, beb, ce);
      const float msk = ((mb >> t) & 1u) ? 1.0f : 0.0f;
      #pragma unroll
      for (int i = 0; i < 4; ++i){
        float p = fexp2(ce[i] * KEXP) * msk;
        float g = frcp(1.0f + fexp2(-cg[i] * KEXP));
        sacc[i] += p;
        P[p_idx(r0 + kg * 4 + i, t * 64 + cres)] = f2bf(p * g);
      }
      __syncthreads();
    }

    #pragma unroll
    for (int i = 0; i < 4; ++i){
      #pragma unroll
      for (int off = 1; off <= 8; off <<= 1)
        sacc[i] += __shfl_xor(sacc[i], off, 64);
    }
    if (arow == 0){
      #pragma unroll
      for (int i = 0; i < 4; ++i)
        ssum[(r0 + kg * 4 + i) * 4 + (wid >> 2)] = sacc[i];
    }
    __syncthreads();

    #pragma unroll
    for (int r = 0; r < 4; ++r){
      const int row = wrow + r;
      float s = ssum[row * 4 + 0] + ssum[row * 4 + 1] + ssum[row * 4 + 2] + ssum[row * 4 + 3];
      float rl = frcp(s);
      if (lane == 0) rls[row] = rl;
      short8 u0 = *(const short8*)&P[p_idx(row, lane * 16)];
      short8 u1 = *(const short8*)&P[p_idx(row, lane * 16 + 8)];
      float rlh = rl * 0.125f;
      #pragma unroll
      for (int j = 0; j < 8; ++j){
        racc[r][j]     += __uint_as_float(((u32)(u16)u0[j]) << 16) * rlh;
        racc[r][8 + j] += __uint_as_float(((u32)(u16)u1[j]) << 16) * rlh;
      }
    }
    __syncthreads();
    float rlv[4];
    #pragma unroll
    for (int i = 0; i < 4; ++i) rlv[i] = rls[r0 + kg * 4 + i];
    __syncthreads();

    const u16* vsrc = Vt + hb * 65536 + (size_t)pv_r * 1024 + pv_c * 8;
    gl_lds16(vsrc, sbase);
    __syncthreads();

    floatx4 cpv = Z4;
    for (int t = 0; t < 8; ++t){
      if (t < 7)
        gl_lds16(vsrc + (size_t)(t + 1) * 128, sbase + (((t + 1) & 1) << 13));
      const u16* vb = stg + ((t & 1) << 13);
      const int swv = (cres & 7) * 8;
      #pragma unroll
      for (int ks = 0; ks < 4; ++ks){
        short8 a  = *(const short8*)&P[p_idx(r0 + arow, t * 128 + ks * 32 + kg * 8)];
        short8 bv = *(const short8*)&vb[cres * 128 + ((ks * 32 + kg * 8) ^ swv)];
        cpv = MFMA16(a, bv, cpv);
      }
      __syncthreads();
    }
    #pragma unroll
    for (int i = 0; i < 4; ++i)
      xa[((size_t)(b * 1024 + qt * 64 + r0 + kg * 4 + i)) * 512 + h * 64 + cres] =
          f2bf(cpv[i] * rlv[i]);
  }

  #pragma unroll
  for (int r = 0; r < 4; ++r){
    const size_t rb = ((size_t)(b * 1024 + qt * 64 + wrow + r)) * 1024 + lane * 16;
    #pragma unroll
    for (int q = 0; q < 4; ++q){
      float4 v = {racc[r][q * 4 + 0], racc[r][q * 4 + 1], racc[r][q * 4 + 2], racc[r][q * 4 + 3]};
      *(float4*)&ratt[rb + q * 4] = v;
    }
  }
}

// ---------------- final FC, 128x128 tile (R14-proven) ----------------
__global__ __launch_bounds__(256) void k_fc(
    const u16* __restrict__ xa, const u16* __restrict__ wt,
    const float* __restrict__ bias, float* __restrict__ out)
{
  __shared__ __align__(16) u16 Asf[128 * 64];
  __shared__ __align__(16) u16 Bsf[128 * 64];
  const int tid = threadIdx.x, lane = tid & 63, wid = tid >> 6;
  const int wm = wid >> 1, wn = wid & 1;
  const int m0 = blockIdx.x * 128, n0 = blockIdx.y * 128;
  const int arow = lane & 15, kg = lane >> 4;
  const int br = tid >> 3, bc = tid & 7;
  u16* const adst = Asf + wid * 512;
  u16* const bdst = Bsf + wid * 512;

  floatx4 acc[4][4];
  #pragma unroll
  for (int i = 0; i < 4; ++i)
    #pragma unroll
    for (int j = 0; j < 4; ++j) acc[i][j] = Z4;

  for (int k0 = 0; k0 < 512; k0 += 64){
    #pragma unroll
    for (int q = 0; q < 4; ++q){
      gl_lds16(xa + (size_t)(m0 + q * 32 + br) * 512 + k0 + ((bc ^ (br & 7)) * 8),
               adst + q * 2048);
      gl_lds16(wt + (size_t)(n0 + q * 32 + br) * 512 + k0 + ((bc ^ (br & 7)) * 8),
               bdst + q * 2048);
    }
    __syncthreads();
    #pragma unroll
    for (int kk = 0; kk < 2; ++kk){
      short8 af[4], bf[4];
      #pragma unroll
      for (int mm = 0; mm < 4; ++mm){
        int rr = wm * 64 + mm * 16 + arow;
        af[mm] = *(const short8*)&Asf[rr * 64 + ((kk * 32 + kg * 8) ^ ((rr & 7) * 8))];
      }
      #pragma unroll
      for (int nn = 0; nn < 4; ++nn){
        int rr = wn * 64 + nn * 16 + arow;
        bf[nn] = *(const short8*)&Bsf[rr * 64 + ((kk * 32 + kg * 8) ^ ((rr & 7) * 8))];
      }
      #pragma unroll
      for (int mm = 0; mm < 4; ++mm)
        #pragma unroll
        for (int nn = 0; nn < 4; ++nn)
          acc[mm][nn] = MFMA16(af[mm], bf[nn], acc[mm][nn]);
    }
    __syncthreads();
  }
  #pragma unroll
  for (int mm = 0; mm < 4; ++mm)
    #pragma unroll
    for (int nn = 0; nn < 4; ++nn){
      int j = n0 + wn * 64 + nn * 16 + arow;
      float bval = bias[j];
      #pragma unroll
      for (int i = 0; i < 4; ++i){
        int sg = m0 + wm * 64 + mm * 16 + kg * 4 + i;
        out[(size_t)sg * 512 + j] = acc[mm][nn][i] + bval;
      }
    }
}

extern "C" void kernel_launch(void* const* d_in, const int* in_sizes, int n_in,
                              void* d_out, int out_size, void* d_ws, size_t ws_size,
                              hipStream_t stream)
{
  const float* query = (const float*)d_in[0];
  const float* key   = (const float*)d_in[1];
  const float* value = (const float*)d_in[2];
  const int*   mask  = (const int*)d_in[3];
  const float* wq  = (const float*)d_in[4];  const float* bq  = (const float*)d_in[5];
  const float* wk  = (const float*)d_in[6];  const float* bk  = (const float*)d_in[7];
  const float* wv  = (const float*)d_in[8];  const float* bv  = (const float*)d_in[9];
  const float* wq1 = (const float*)d_in[10]; const float* bq1 = (const float*)d_in[11];
  const float* wk1 = (const float*)d_in[12]; const float* bk1 = (const float*)d_in[13];
  const float* wfc = (const float*)d_in[14]; const float* bfc = (const float*)d_in[15];

  u16* ws  = (u16*)d_ws;
  u16* Qh  = ws;
  u16* Kh  = Qh  + 8388608;
  u16* Vt  = Kh  + 8388608;
  u16* Q1h = Vt  + 8388608;
  u16* K1h = Q1h + 8388608;
  u16* xa  = K1h + 8388608;
  u16* wts = xa  + 8388608;           // 6 * 262144 u16
  u16* U   = wts + 6 * 262144;        // 134217728 u16 = 268 MB (split path only)
  float* rsum = (float*)(U + 134217728);  // 131072 f32

  const size_t need_split = (size_t)(51904512 + 134217728) * 2 + 524288;  // ~373 MB

  float* outx = (float*)d_out;
  float* ratt = outx + 8388608;

  k_wt6<<<dim3(1024, 6), dim3(256), 0, stream>>>(wq, wk, wv, wq1, wk1, wfc, wts);

  k_proj<<<dim3(128, 4, 5), dim3(256), 0, stream>>>(
      query, key, value, wts, bq, bk, bv, bq1, bk1, Qh, Kh, Vt, Q1h, K1h);

  if (ws_size >= need_split){
    k_qk<<<dim3(16, 16, 8), dim3(1024), 0, stream>>>(
        Qh, Kh, Q1h, K1h, mask, U, rsum);
    k_pvr<<<dim3(16, 32), dim3(512), 0, stream>>>(
        U, rsum, Vt, xa, ratt);
  } else {
    (void)hipFuncSetAttribute((const void*)k_attn,
                              hipFuncAttributeMaxDynamicSharedMemorySize, 163840);
    k_attn<<<dim3(16, 16), dim3(1024), 163840, stream>>>(
        Qh, Kh, Vt, Q1h, K1h, mask, xa, ratt);
  }

  k_fc<<<dim3(128, 4), dim3(256), 0, stream>>>(
      xa, wts + 5 * 262144, bfc, outx);
}

// Round 16
// 453.749 us; speedup vs baseline: 1.3036x; 1.3036x over previous
//
#include <hip/hip_runtime.h>
#include <hip/hip_bf16.h>

typedef unsigned short u16;
typedef unsigned int u32;
typedef unsigned long long u64;
typedef __attribute__((ext_vector_type(8))) short short8;
typedef __attribute__((ext_vector_type(4))) float floatx4;

#define MFMA16(a,b,c) __builtin_amdgcn_mfma_f32_16x16x32_bf16((a),(b),(c),0,0,0)

__device__ __forceinline__ u16 f2bf(float f){
  u32 x = __float_as_uint(f);
  x += 0x7FFFu + ((x >> 16) & 1u);
  return (u16)(x >> 16);
}
__device__ __forceinline__ float frcp(float x){ return __builtin_amdgcn_rcpf(x); }
__device__ __forceinline__ float fexp2(float x){ return __builtin_amdgcn_exp2f(x); }
// 0.125 * log2(e): scale folded into the exp2 argument
#define KEXP 0.18033688011112042f
#define Z4 ((floatx4){0.f,0.f,0.f,0.f})

// async global->LDS 16B per lane: LDS dest = wave-uniform base + lane*16,
// global src is per-lane (pre-swizzled source pattern).
__device__ __forceinline__ void gl_lds16(const u16* src, u16* dst){
  __builtin_amdgcn_global_load_lds(
      (const __attribute__((address_space(1))) unsigned int*)(u64)(src),
      (__attribute__((address_space(3))) unsigned int*)(u32)(u64)(dst),
      16, 0, 0);
}

// P-buffer swizzle (mono fallback): 16-elem (32B) windows XORed by (row>>2)&3.
__device__ __forceinline__ int p_idx(int row, int col){
  return row * 1024 + (col ^ (((row >> 2) & 3) << 4));
}

// ---------------- weight transpose+convert (all 6): wt[z][j][d] = bf16(w[z][d][j]) ----
__global__ __launch_bounds__(256) void k_wt6(
    const float* __restrict__ w0, const float* __restrict__ w1, const float* __restrict__ w2,
    const float* __restrict__ w3, const float* __restrict__ w4, const float* __restrict__ w5,
    u16* __restrict__ wts)
{
  int z = blockIdx.y;
  const float* w;
  switch (z){ case 0: w = w0; break; case 1: w = w1; break; case 2: w = w2; break;
              case 3: w = w3; break; case 4: w = w4; break; default: w = w5; break; }
  int idx = blockIdx.x * 256 + threadIdx.x;
  int j = idx >> 9, d = idx & 511;
  wts[(size_t)z * 262144 + idx] = f2bf(w[d * 512 + j]);
}

// ---------------- 5-way projection GEMM, 128x128 tile (R14-proven) ----------------
__global__ __launch_bounds__(256) void k_proj(
    const float* __restrict__ xq, const float* __restrict__ xk, const float* __restrict__ xv,
    const u16* __restrict__ wts,
    const float* __restrict__ bq, const float* __restrict__ bk, const float* __restrict__ bv,
    const float* __restrict__ bq1, const float* __restrict__ bk1,
    u16* __restrict__ Qh, u16* __restrict__ Kh, u16* __restrict__ Vt,
    u16* __restrict__ Q1h, u16* __restrict__ K1h)
{
  __shared__ __align__(16) u16 As[128][72];
  __shared__ __align__(16) u16 Bs[128 * 64];
  int z = blockIdx.z;
  const float* x; const float* bias; u16* out; int vtm = 0;
  switch (z){
    case 0: x = xq; bias = bq;  out = Qh;  break;
    case 1: x = xk; bias = bk;  out = Kh;  break;
    case 2: x = xv; bias = bv;  out = Vt;  vtm = 1; break;
    case 3: x = xq; bias = bq1; out = Q1h; break;
    default: x = xk; bias = bk1; out = K1h; break;
  }
  const u16* wt = wts + (size_t)z * 262144;
  const int tid = threadIdx.x, lane = tid & 63, wid = tid >> 6;
  const int wm = wid >> 1, wn = wid & 1;
  const int m0 = blockIdx.x * 128, n0 = blockIdx.y * 128;
  const int arow = lane & 15, kg = lane >> 4;
  const int ar = tid >> 1, ah = (tid & 1) * 32;
  const int br = tid >> 3, bc = tid & 7;
  u16* const bdst = Bs + wid * 512;

  floatx4 acc[4][4];
  #pragma unroll
  for (int i = 0; i < 4; ++i)
    #pragma unroll
    for (int j = 0; j < 4; ++j) acc[i][j] = Z4;

  for (int k0 = 0; k0 < 512; k0 += 64){
    #pragma unroll
    for (int q = 0; q < 4; ++q)
      gl_lds16(wt + (size_t)(n0 + q * 32 + br) * 512 + k0 + ((bc ^ (br & 7)) * 8),
               bdst + q * 2048);
    const float4* xp = (const float4*)(x + (size_t)(m0 + ar) * 512 + k0 + ah);
    #pragma unroll
    for (int j = 0; j < 4; ++j){
      float4 f0 = xp[2 * j], f1 = xp[2 * j + 1];
      short8 v;
      v[0] = (short)f2bf(f0.x); v[1] = (short)f2bf(f0.y);
      v[2] = (short)f2bf(f0.z); v[3] = (short)f2bf(f0.w);
      v[4] = (short)f2bf(f1.x); v[5] = (short)f2bf(f1.y);
      v[6] = (short)f2bf(f1.z); v[7] = (short)f2bf(f1.w);
      *(short8*)&As[ar][ah + j * 8] = v;
    }
    __syncthreads();
    #pragma unroll
    for (int kk = 0; kk < 2; ++kk){
      short8 af[4], bf[4];
      #pragma unroll
      for (int mm = 0; mm < 4; ++mm)
        af[mm] = *(const short8*)&As[wm * 64 + mm * 16 + arow][kk * 32 + kg * 8];
      #pragma unroll
      for (int nn = 0; nn < 4; ++nn){
        int rr = wn * 64 + nn * 16 + arow;
        bf[nn] = *(const short8*)&Bs[rr * 64 + ((kk * 32 + kg * 8) ^ ((rr & 7) * 8))];
      }
      #pragma unroll
      for (int mm = 0; mm < 4; ++mm)
        #pragma unroll
        for (int nn = 0; nn < 4; ++nn)
          acc[mm][nn] = MFMA16(af[mm], bf[nn], acc[mm][nn]);
    }
    __syncthreads();
  }
  #pragma unroll
  for (int mm = 0; mm < 4; ++mm)
    #pragma unroll
    for (int nn = 0; nn < 4; ++nn){
      int j = n0 + wn * 64 + nn * 16 + arow;
      int h = j >> 6, dh = j & 63;
      float bval = bias[j];
      #pragma unroll
      for (int i = 0; i < 4; ++i){
        int sg = m0 + wm * 64 + mm * 16 + kg * 4 + i;
        int bb = sg >> 10, s = sg & 1023;
        float val = acc[mm][nn][i] + bval;
        size_t o = vtm ? (((size_t)((bb << 3) + h) * 64 + dh) * 1024 + s)
                       : (((size_t)((bb << 3) + h) * 1024 + s) * 64 + dh);
        out[o] = f2bf(val);
      }
    }
}

// ================= SPLIT PATH =================
// ---------------- kernel A: dual-QK logits -> u = exp*sigmoid -> U, rsum -------------
// grid (16 b, 16 qt, 8 h) = 2048 blocks; 1024 thr; 33 KB LDS -> 2 blocks/CU.
__global__ void __launch_bounds__(1024)
k_qk(const u16* __restrict__ Qh, const u16* __restrict__ Kh,
     const u16* __restrict__ Q1h, const u16* __restrict__ K1h,
     const int* __restrict__ mask, u16* __restrict__ U, float* __restrict__ rsum)
{
  __shared__ __align__(16) u16 stg[2 * 8192];
  __shared__ float ssum[64 * 4];

  const int tid = threadIdx.x, lane = tid & 63, wid = tid >> 6;
  const int arow = lane & 15, kg = lane >> 4;
  const int b = blockIdx.x, qt = blockIdx.y, h = blockIdx.z;
  const int r0 = (wid & 3) * 16;
  const int cres = ((wid >> 2) * 16) + arow;

  const int ls_half = tid >> 9;
  const int ls_r = (tid & 511) >> 3;
  const int ls_c = (tid & 7) ^ (ls_r & 7);
  u16* const sbase = stg + wid * 512;

  u32 mb = 0;
  #pragma unroll
  for (int t = 0; t < 16; ++t)
    mb |= (mask[b * 1024 + t * 64 + cres] != 0 ? 1u : 0u) << t;

  const size_t hb = (size_t)(b * 8 + h);
  const u16* qp  = Qh  + (hb * 1024 + qt * 64 + r0 + arow) * 64 + kg * 8;
  const u16* q1p = Q1h + (hb * 1024 + qt * 64 + r0 + arow) * 64 + kg * 8;
  short8 aq0 = *(const short8*)qp,  aq1 = *(const short8*)(qp + 32);
  short8 ap0 = *(const short8*)q1p, ap1 = *(const short8*)(q1p + 32);

  const u16* lsrc = (ls_half ? Kh : K1h) + hb * 65536 + (size_t)ls_r * 64 + ls_c * 8;
  u16* const ubase = U + hb * 1048576;

  gl_lds16(lsrc, sbase);
  __syncthreads();

  float sacc[4] = {0.f, 0.f, 0.f, 0.f};
  for (int t = 0; t < 16; ++t){
    if (t < 15)
      gl_lds16(lsrc + (size_t)(t + 1) * 4096, sbase + (((t + 1) & 1) << 13));
    const u16* kb = stg + ((t & 1) << 13);
    const int swl = (cres & 7) * 8;
    short8 b1a = *(const short8*)&kb[cres * 64 + ((     kg * 8) ^ swl)];
    short8 b1b = *(const short8*)&kb[cres * 64 + ((32 + kg * 8) ^ swl)];
    short8 bea = *(const short8*)&kb[4096 + cres * 64 + ((     kg * 8) ^ swl)];
    short8 beb = *(const short8*)&kb[4096 + cres * 64 + ((32 + kg * 8) ^ swl)];
    floatx4 cg = Z4, ce = Z4;
    cg = MFMA16(ap0, b1a, cg); cg = MFMA16(ap1, b1b, cg);
    ce = MFMA16(aq0, bea, ce); ce = MFMA16(aq1, beb, ce);
    const float msk = ((mb >> t) & 1u) ? 1.0f : 0.0f;
    #pragma unroll
    for (int i = 0; i < 4; ++i){
      float p = fexp2(ce[i] * KEXP) * msk;
      float g = frcp(1.0f + fexp2(-cg[i] * KEXP));
      sacc[i] += p;
      ubase[(size_t)(qt * 64 + r0 + kg * 4 + i) * 1024 + t * 64 + cres] = f2bf(p * g);
    }
    __syncthreads();
  }

  #pragma unroll
  for (int i = 0; i < 4; ++i){
    #pragma unroll
    for (int off = 1; off <= 8; off <<= 1)
      sacc[i] += __shfl_xor(sacc[i], off, 64);
  }
  if (arow == 0){
    #pragma unroll
    for (int i = 0; i < 4; ++i)
      ssum[(r0 + kg * 4 + i) * 4 + (wid >> 2)] = sacc[i];
  }
  __syncthreads();
  if (tid < 64){
    float s = ssum[tid * 4 + 0] + ssum[tid * 4 + 1] + ssum[tid * 4 + 2] + ssum[tid * 4 + 3];
    rsum[hb * 1024 + qt * 64 + tid] = s;
  }
}

// ---------------- kernel B v2: r_att + PV, BOTH from STAGED U tiles -------------
// grid (16 b, 32 qt); 512 thr (8 waves); 48 KB LDS dbuf -> 2 blocks/CU.
// Per (head, t): stage {U-slice 32x128 (8KB) + V-tile 64x128 (16KB)} via gl_lds16,
// R6-proven issue-ahead + __syncthreads loop. racc reads the staged U (u32, 2-way
// bank = free) — kills R15's second 268 MB HBM pass; PV A-frags read staged U too
// (R15 demand-global A-frags were the 309 us latency serialization).
__global__ void __launch_bounds__(512)
__attribute__((amdgpu_waves_per_eu(4, 4)))
k_pvr(const u16* __restrict__ U, const float* __restrict__ rsum,
      const u16* __restrict__ Vt, u16* __restrict__ xa, float* __restrict__ ratt)
{
  extern __shared__ __align__(16) u16 stg2[];   // 2 bufs x 12288 u16: U[0,4096) V[4096,12288)

  const int tid = threadIdx.x, lane = tid & 63, wid = tid >> 6;
  const int arow = lane & 15, kg = lane >> 4;
  const int b = blockIdx.x, qt = blockIdx.y;
  const int s2 = wid & 1, cg = wid >> 1;
  const int cres = cg * 16 + arow;          // dh residue
  const int wrow = wid * 4;                 // racc rows
  const int a_r = s2 * 16 + arow;           // PV A row in U slice

  // U staging: row ur (0..31 of the 32-row slice), 16B chunk (swizzled src)
  const int ur = tid >> 4, uc = (tid & 15) ^ (ur & 7);
  // V staging (2 issues of 8KB): rows 0..31 then 32..63
  const int vr0 = tid >> 4, vc0 = (tid & 15) ^ (vr0 & 7);
  const int vr1 = vr0 + 32, vc1 = (tid & 15) ^ (vr1 & 7);

  float racc[4][16];
  #pragma unroll
  for (int r = 0; r < 4; ++r)
    #pragma unroll
    for (int j = 0; j < 16; ++j) racc[r][j] = 0.f;

  for (int h = 0; h < 8; ++h){
    const size_t hb = (size_t)(b * 8 + h);
    const u16* ub = U  + hb * 1048576 + (size_t)(qt * 32) * 1024;
    const u16* vb = Vt + hb * 65536;

    float rlh[4], rlx[4];
    #pragma unroll
    for (int r = 0; r < 4; ++r)
      rlh[r] = frcp(rsum[hb * 1024 + qt * 32 + wrow + r]) * 0.125f;
    #pragma unroll
    for (int i = 0; i < 4; ++i)
      rlx[i] = frcp(rsum[hb * 1024 + qt * 32 + s2 * 16 + kg * 4 + i]);

    // prologue: stage tile 0 -> buf 0
    gl_lds16(ub + (size_t)ur * 1024 + uc * 8,  stg2 + tid * 8);
    gl_lds16(vb + (size_t)vr0 * 1024 + vc0 * 8, stg2 + 4096 + tid * 8);
    gl_lds16(vb + (size_t)vr1 * 1024 + vc1 * 8, stg2 + 8192 + tid * 8);
    __syncthreads();

    floatx4 cpv = Z4;
    for (int t = 0; t < 8; ++t){
      if (t < 7){
        const int nb = ((t + 1) & 1) * 12288;
        gl_lds16(ub + (size_t)ur * 1024 + (t + 1) * 128 + uc * 8,  stg2 + nb + tid * 8);
        gl_lds16(vb + (size_t)vr0 * 1024 + (t + 1) * 128 + vc0 * 8, stg2 + nb + 4096 + tid * 8);
        gl_lds16(vb + (size_t)vr1 * 1024 + (t + 1) * 128 + vc1 * 8, stg2 + nb + 8192 + tid * 8);
      }
      const u16* Ut  = stg2 + (t & 1) * 12288;
      const u16* Vts = Ut + 4096;
      // racc from staged U (col = t*128 + lane*2 (+1))
      #pragma unroll
      for (int r = 0; r < 4; ++r){
        const int row = wrow + r;
        u32 w = *(const u32*)&Ut[row * 128 + ((lane * 2) ^ ((row & 7) * 8))];
        racc[r][2 * t]     += __uint_as_float(w << 16) * rlh[r];
        racc[r][2 * t + 1] += __uint_as_float(w & 0xFFFF0000u) * rlh[r];
      }
      // PV MFMA from staged U + V
      #pragma unroll
      for (int ks = 0; ks < 4; ++ks){
        short8 a  = *(const short8*)&Ut[a_r * 128 + ((ks * 32 + kg * 8) ^ ((a_r & 7) * 8))];
        short8 bv = *(const short8*)&Vts[cres * 128 + ((ks * 32 + kg * 8) ^ ((cres & 7) * 8))];
        cpv = MFMA16(a, bv, cpv);
      }
      __syncthreads();
    }
    // epilogue: scale by 1/sum, write xa
    #pragma unroll
    for (int i = 0; i < 4; ++i){
      const int g = qt * 32 + s2 * 16 + kg * 4 + i;
      xa[((size_t)(b * 1024 + g)) * 512 + h * 64 + cres] = f2bf(cpv[i] * rlx[i]);
    }
  }

  // r_att writeout (float2-coalesced: col = t*128 + lane*2 + par)
  #pragma unroll
  for (int r = 0; r < 4; ++r){
    const size_t rb = ((size_t)(b * 1024 + qt * 32 + wrow + r)) * 1024;
    #pragma unroll
    for (int j = 0; j < 8; ++j){
      float2 v = {racc[r][2 * j], racc[r][2 * j + 1]};
      *(float2*)&ratt[rb + j * 128 + lane * 2] = v;
    }
  }
}

// ================= MONO FALLBACK (R6/R14-proven, 362 us) =================
__global__ void __launch_bounds__(1024)
__attribute__((amdgpu_waves_per_eu(4, 4)))
k_attn(
    const u16* __restrict__ Qh, const u16* __restrict__ Kh, const u16* __restrict__ Vt,
    const u16* __restrict__ Q1h, const u16* __restrict__ K1h,
    const int* __restrict__ mask, u16* __restrict__ xa, float* __restrict__ ratt)
{
  extern __shared__ __align__(16) char smem[];
  u16* P   = (u16*)smem;
  u16* stg = (u16*)(smem + 131072);
  float* ssum = (float*)(smem + 131072);
  float* rls  = (float*)(smem + 131072 + 1024);

  const int tid = threadIdx.x, lane = tid & 63, wid = tid >> 6;
  const int arow = lane & 15, kg = lane >> 4;
  const int b = blockIdx.x, qt = blockIdx.y;
  const int r0 = (wid & 3) * 16;
  const int cres = ((wid >> 2) * 16) + arow;
  const int wrow = wid * 4;

  const int ls_half = tid >> 9;
  const int ls_r = (tid & 511) >> 3;
  const int ls_c = (tid & 7) ^ (ls_r & 7);
  const int pv_r = tid >> 4;
  const int pv_c = (tid & 15) ^ (pv_r & 7);
  u16* const sbase = stg + wid * 512;

  u32 mb = 0;
  #pragma unroll
  for (int t = 0; t < 16; ++t)
    mb |= (mask[b * 1024 + t * 64 + cres] != 0 ? 1u : 0u) << t;

  float racc[4][16];
  #pragma unroll
  for (int r = 0; r < 4; ++r)
    #pragma unroll
    for (int j = 0; j < 16; ++j) racc[r][j] = 0.f;

  for (int h = 0; h < 8; ++h){
    const size_t hb = (size_t)(b * 8 + h);
    const u16* qp  = Qh  + (hb * 1024 + qt * 64 + r0 + arow) * 64 + kg * 8;
    const u16* q1p = Q1h + (hb * 1024 + qt * 64 + r0 + arow) * 64 + kg * 8;
    short8 aq0 = *(const short8*)qp,  aq1 = *(const short8*)(qp + 32);
    short8 ap0 = *(const short8*)q1p, ap1 = *(const short8*)(q1p + 32);

    const u16* lsrc = (ls_half ? Kh : K1h) + hb * 65536 + (size_t)ls_r * 64 + ls_c * 8;

    gl_lds16(lsrc, sbase);
    __syncthreads();

    float sacc[4] = {0.f, 0.f, 0.f, 0.f};
    for (int t = 0; t < 16; ++t){
      if (t < 15)
        gl_lds16(lsrc + (size_t)(t + 1) * 4096, sbase + (((t + 1) & 1) << 13));
      const u16* kb = stg + ((t & 1) << 13);
      const int swl = (cres & 7) * 8;
      short8 b1a = *(const short8*)&kb[cres * 64 + ((     kg * 8) ^ swl)];
      short8 b1b = *(const short8*)&kb[cres * 64 + ((32 + kg * 8) ^ swl)];
      short8 bea = *(const short8*)&kb[4096 + cres * 64 + ((     kg * 8) ^ swl)];
      short8 beb = *(const short8*)&kb[4096 + cres * 64 + ((32 + kg * 8) ^ swl)];
      floatx4 cg = Z4, ce = Z4;
      cg = MFMA16(ap0, b1a, cg); cg = MFMA16(ap1, b1b, cg);
      ce = MFMA16(aq0, bea, ce); ce = MFMA16(aq1, beb, ce);
      const float msk = ((mb >> t) & 1u) ? 1.0f : 0.0f;
      #pragma unroll
      for (int i = 0; i < 4; ++i){
        float p = fexp2(ce[i] * KEXP) * msk;
        float g = frcp(1.0f + fexp2(-cg[i] * KEXP));
        sacc[i] += p;
        P[p_idx(r0 + kg * 4 + i, t * 64 + cres)] = f2bf(p * g);
      }
      __syncthreads();
    }

    #pragma unroll
    for (int i = 0; i < 4; ++i){
      #pragma unroll
      for (int off = 1; off <= 8; off <<= 1)
        sacc[i] += __shfl_xor(sacc[i], off, 64);
    }
    if (arow == 0){
      #pragma unroll
      for (int i = 0; i < 4; ++i)
        ssum[(r0 + kg * 4 + i) * 4 + (wid >> 2)] = sacc[i];
    }
    __syncthreads();

    #pragma unroll
    for (int r = 0; r < 4; ++r){
      const int row = wrow + r;
      float s = ssum[row * 4 + 0] + ssum[row * 4 + 1] + ssum[row * 4 + 2] + ssum[row * 4 + 3];
      float rl = frcp(s);
      if (lane == 0) rls[row] = rl;
      short8 u0 = *(const short8*)&P[p_idx(row, lane * 16)];
      short8 u1 = *(const short8*)&P[p_idx(row, lane * 16 + 8)];
      float rlh = rl * 0.125f;
      #pragma unroll
      for (int j = 0; j < 8; ++j){
        racc[r][j]     += __uint_as_float(((u32)(u16)u0[j]) << 16) * rlh;
        racc[r][8 + j] += __uint_as_float(((u32)(u16)u1[j]) << 16) * rlh;
      }
    }
    __syncthreads();
    float rlv[4];
    #pragma unroll
    for (int i = 0; i < 4; ++i) rlv[i] = rls[r0 + kg * 4 + i];
    __syncthreads();

    const u16* vsrc = Vt + hb * 65536 + (size_t)pv_r * 1024 + pv_c * 8;
    gl_lds16(vsrc, sbase);
    __syncthreads();

    floatx4 cpv = Z4;
    for (int t = 0; t < 8; ++t){
      if (t < 7)
        gl_lds16(vsrc + (size_t)(t + 1) * 128, sbase + (((t + 1) & 1) << 13));
      const u16* vb = stg + ((t & 1) << 13);
      const int swv = (cres & 7) * 8;
      #pragma unroll
      for (int ks = 0; ks < 4; ++ks){
        short8 a  = *(const short8*)&P[p_idx(r0 + arow, t * 128 + ks * 32 + kg * 8)];
        short8 bv = *(const short8*)&vb[cres * 128 + ((ks * 32 + kg * 8) ^ swv)];
        cpv = MFMA16(a, bv, cpv);
      }
      __syncthreads();
    }
    #pragma unroll
    for (int i = 0; i < 4; ++i)
      xa[((size_t)(b * 1024 + qt * 64 + r0 + kg * 4 + i)) * 512 + h * 64 + cres] =
          f2bf(cpv[i] * rlv[i]);
  }

  #pragma unroll
  for (int r = 0; r < 4; ++r){
    const size_t rb = ((size_t)(b * 1024 + qt * 64 + wrow + r)) * 1024 + lane * 16;
    #pragma unroll
    for (int q = 0; q < 4; ++q){
      float4 v = {racc[r][q * 4 + 0], racc[r][q * 4 + 1], racc[r][q * 4 + 2], racc[r][q * 4 + 3]};
      *(float4*)&ratt[rb + q * 4] = v;
    }
  }
}

// ---------------- final FC, 128x128 tile (R14-proven) ----------------
__global__ __launch_bounds__(256) void k_fc(
    const u16* __restrict__ xa, const u16* __restrict__ wt,
    const float* __restrict__ bias, float* __restrict__ out)
{
  __shared__ __align__(16) u16 Asf[128 * 64];
  __shared__ __align__(16) u16 Bsf[128 * 64];
  const int tid = threadIdx.x, lane = tid & 63, wid = tid >> 6;
  const int wm = wid >> 1, wn = wid & 1;
  const int m0 = blockIdx.x * 128, n0 = blockIdx.y * 128;
  const int arow = lane & 15, kg = lane >> 4;
  const int br = tid >> 3, bc = tid & 7;
  u16* const adst = Asf + wid * 512;
  u16* const bdst = Bsf + wid * 512;

  floatx4 acc[4][4];
  #pragma unroll
  for (int i = 0; i < 4; ++i)
    #pragma unroll
    for (int j = 0; j < 4; ++j) acc[i][j] = Z4;

  for (int k0 = 0; k0 < 512; k0 += 64){
    #pragma unroll
    for (int q = 0; q < 4; ++q){
      gl_lds16(xa + (size_t)(m0 + q * 32 + br) * 512 + k0 + ((bc ^ (br & 7)) * 8),
               adst + q * 2048);
      gl_lds16(wt + (size_t)(n0 + q * 32 + br) * 512 + k0 + ((bc ^ (br & 7)) * 8),
               bdst + q * 2048);
    }
    __syncthreads();
    #pragma unroll
    for (int kk = 0; kk < 2; ++kk){
      short8 af[4], bf[4];
      #pragma unroll
      for (int mm = 0; mm < 4; ++mm){
        int rr = wm * 64 + mm * 16 + arow;
        af[mm] = *(const short8*)&Asf[rr * 64 + ((kk * 32 + kg * 8) ^ ((rr & 7) * 8))];
      }
      #pragma unroll
      for (int nn = 0; nn < 4; ++nn){
        int rr = wn * 64 + nn * 16 + arow;
        bf[nn] = *(const short8*)&Bsf[rr * 64 + ((kk * 32 + kg * 8) ^ ((rr & 7) * 8))];
      }
      #pragma unroll
      for (int mm = 0; mm < 4; ++mm)
        #pragma unroll
        for (int nn = 0; nn < 4; ++nn)
          acc[mm][nn] = MFMA16(af[mm], bf[nn], acc[mm][nn]);
    }
    __syncthreads();
  }
  #pragma unroll
  for (int mm = 0; mm < 4; ++mm)
    #pragma unroll
    for (int nn = 0; nn < 4; ++nn){
      int j = n0 + wn * 64 + nn * 16 + arow;
      float bval = bias[j];
      #pragma unroll
      for (int i = 0; i < 4; ++i){
        int sg = m0 + wm * 64 + mm * 16 + kg * 4 + i;
        out[(size_t)sg * 512 + j] = acc[mm][nn][i] + bval;
      }
    }
}

extern "C" void kernel_launch(void* const* d_in, const int* in_sizes, int n_in,
                              void* d_out, int out_size, void* d_ws, size_t ws_size,
                              hipStream_t stream)
{
  const float* query = (const float*)d_in[0];
  const float* key   = (const float*)d_in[1];
  const float* value = (const float*)d_in[2];
  const int*   mask  = (const int*)d_in[3];
  const float* wq  = (const float*)d_in[4];  const float* bq  = (const float*)d_in[5];
  const float* wk  = (const float*)d_in[6];  const float* bk  = (const float*)d_in[7];
  const float* wv  = (const float*)d_in[8];  const float* bv  = (const float*)d_in[9];
  const float* wq1 = (const float*)d_in[10]; const float* bq1 = (const float*)d_in[11];
  const float* wk1 = (const float*)d_in[12]; const float* bk1 = (const float*)d_in[13];
  const float* wfc = (const float*)d_in[14]; const float* bfc = (const float*)d_in[15];

  u16* ws  = (u16*)d_ws;
  u16* Qh  = ws;
  u16* Kh  = Qh  + 8388608;
  u16* Vt  = Kh  + 8388608;
  u16* Q1h = Vt  + 8388608;
  u16* K1h = Q1h + 8388608;
  u16* xa  = K1h + 8388608;
  u16* wts = xa  + 8388608;           // 6 * 262144 u16
  u16* U   = wts + 6 * 262144;        // 134217728 u16 = 268 MB (split path only)
  float* rsum = (float*)(U + 134217728);  // 131072 f32

  const size_t need_split = (size_t)(51904512 + 134217728) * 2 + 524288;  // ~373 MB

  float* outx = (float*)d_out;
  float* ratt = outx + 8388608;

  k_wt6<<<dim3(1024, 6), dim3(256), 0, stream>>>(wq, wk, wv, wq1, wk1, wfc, wts);

  k_proj<<<dim3(128, 4, 5), dim3(256), 0, stream>>>(
      query, key, value, wts, bq, bk, bv, bq1, bk1, Qh, Kh, Vt, Q1h, K1h);

  if (ws_size >= need_split){
    (void)hipFuncSetAttribute((const void*)k_pvr,
                              hipFuncAttributeMaxDynamicSharedMemorySize, 49152);
    k_qk<<<dim3(16, 16, 8), dim3(1024), 0, stream>>>(
        Qh, Kh, Q1h, K1h, mask, U, rsum);
    k_pvr<<<dim3(16, 32), dim3(512), 49152, stream>>>(
        U, rsum, Vt, xa, ratt);
  } else {
    (void)hipFuncSetAttribute((const void*)k_attn,
                              hipFuncAttributeMaxDynamicSharedMemorySize, 163840);
    k_attn<<<dim3(16, 16), dim3(1024), 163840, stream>>>(
        Qh, Kh, Vt, Q1h, K1h, mask, xa, ratt);
  }

  k_fc<<<dim3(128, 4), dim3(256), 0, stream>>>(
      xa, wts + 5 * 262144, bfc, outx);
}

// Round 17
// 437.318 us; speedup vs baseline: 1.3526x; 1.0376x over previous
//
#include <hip/hip_runtime.h>
#include <hip/hip_bf16.h>

typedef unsigned short u16;
typedef unsigned int u32;
typedef unsigned long long u64;
typedef __attribute__((ext_vector_type(8))) short short8;
typedef __attribute__((ext_vector_type(4))) float floatx4;

#define MFMA16(a,b,c) __builtin_amdgcn_mfma_f32_16x16x32_bf16((a),(b),(c),0,0,0)

__device__ __forceinline__ u16 f2bf(float f){
  u32 x = __float_as_uint(f);
  x += 0x7FFFu + ((x >> 16) & 1u);
  return (u16)(x >> 16);
}
__device__ __forceinline__ float frcp(float x){ return __builtin_amdgcn_rcpf(x); }
__device__ __forceinline__ float fexp2(float x){ return __builtin_amdgcn_exp2f(x); }
// 0.125 * log2(e): scale folded into the exp2 argument
#define KEXP 0.18033688011112042f
#define Z4 ((floatx4){0.f,0.f,0.f,0.f})

// async global->LDS 16B per lane: LDS dest = wave-uniform base + lane*16,
// global src is per-lane (pre-swizzled source pattern).
__device__ __forceinline__ void gl_lds16(const u16* src, u16* dst){
  __builtin_amdgcn_global_load_lds(
      (const __attribute__((address_space(1))) unsigned int*)(u64)(src),
      (__attribute__((address_space(3))) unsigned int*)(u32)(u64)(dst),
      16, 0, 0);
}

// P-buffer swizzle (mono fallback): 16-elem (32B) windows XORed by (row>>2)&3.
__device__ __forceinline__ int p_idx(int row, int col){
  return row * 1024 + (col ^ (((row >> 2) & 3) << 4));
}

// ---------------- weight transpose+convert (all 6): wt[z][j][d] = bf16(w[z][d][j]) ----
__global__ __launch_bounds__(256) void k_wt6(
    const float* __restrict__ w0, const float* __restrict__ w1, const float* __restrict__ w2,
    const float* __restrict__ w3, const float* __restrict__ w4, const float* __restrict__ w5,
    u16* __restrict__ wts)
{
  int z = blockIdx.y;
  const float* w;
  switch (z){ case 0: w = w0; break; case 1: w = w1; break; case 2: w = w2; break;
              case 3: w = w3; break; case 4: w = w4; break; default: w = w5; break; }
  int idx = blockIdx.x * 256 + threadIdx.x;
  int j = idx >> 9, d = idx & 511;
  wts[(size_t)z * 262144 + idx] = f2bf(w[d * 512 + j]);
}

// ---------------- 5-way projection GEMM, 128x128 tile (R14-proven) ----------------
__global__ __launch_bounds__(256) void k_proj(
    const float* __restrict__ xq, const float* __restrict__ xk, const float* __restrict__ xv,
    const u16* __restrict__ wts,
    const float* __restrict__ bq, const float* __restrict__ bk, const float* __restrict__ bv,
    const float* __restrict__ bq1, const float* __restrict__ bk1,
    u16* __restrict__ Qh, u16* __restrict__ Kh, u16* __restrict__ Vt,
    u16* __restrict__ Q1h, u16* __restrict__ K1h)
{
  __shared__ __align__(16) u16 As[128][72];
  __shared__ __align__(16) u16 Bs[128 * 64];
  int z = blockIdx.z;
  const float* x; const float* bias; u16* out; int vtm = 0;
  switch (z){
    case 0: x = xq; bias = bq;  out = Qh;  break;
    case 1: x = xk; bias = bk;  out = Kh;  break;
    case 2: x = xv; bias = bv;  out = Vt;  vtm = 1; break;
    case 3: x = xq; bias = bq1; out = Q1h; break;
    default: x = xk; bias = bk1; out = K1h; break;
  }
  const u16* wt = wts + (size_t)z * 262144;
  const int tid = threadIdx.x, lane = tid & 63, wid = tid >> 6;
  const int wm = wid >> 1, wn = wid & 1;
  const int m0 = blockIdx.x * 128, n0 = blockIdx.y * 128;
  const int arow = lane & 15, kg = lane >> 4;
  const int ar = tid >> 1, ah = (tid & 1) * 32;
  const int br = tid >> 3, bc = tid & 7;
  u16* const bdst = Bs + wid * 512;

  floatx4 acc[4][4];
  #pragma unroll
  for (int i = 0; i < 4; ++i)
    #pragma unroll
    for (int j = 0; j < 4; ++j) acc[i][j] = Z4;

  for (int k0 = 0; k0 < 512; k0 += 64){
    #pragma unroll
    for (int q = 0; q < 4; ++q)
      gl_lds16(wt + (size_t)(n0 + q * 32 + br) * 512 + k0 + ((bc ^ (br & 7)) * 8),
               bdst + q * 2048);
    const float4* xp = (const float4*)(x + (size_t)(m0 + ar) * 512 + k0 + ah);
    #pragma unroll
    for (int j = 0; j < 4; ++j){
      float4 f0 = xp[2 * j], f1 = xp[2 * j + 1];
      short8 v;
      v[0] = (short)f2bf(f0.x); v[1] = (short)f2bf(f0.y);
      v[2] = (short)f2bf(f0.z); v[3] = (short)f2bf(f0.w);
      v[4] = (short)f2bf(f1.x); v[5] = (short)f2bf(f1.y);
      v[6] = (short)f2bf(f1.z); v[7] = (short)f2bf(f1.w);
      *(short8*)&As[ar][ah + j * 8] = v;
    }
    __syncthreads();
    #pragma unroll
    for (int kk = 0; kk < 2; ++kk){
      short8 af[4], bf[4];
      #pragma unroll
      for (int mm = 0; mm < 4; ++mm)
        af[mm] = *(const short8*)&As[wm * 64 + mm * 16 + arow][kk * 32 + kg * 8];
      #pragma unroll
      for (int nn = 0; nn < 4; ++nn){
        int rr = wn * 64 + nn * 16 + arow;
        bf[nn] = *(const short8*)&Bs[rr * 64 + ((kk * 32 + kg * 8) ^ ((rr & 7) * 8))];
      }
      #pragma unroll
      for (int mm = 0; mm < 4; ++mm)
        #pragma unroll
        for (int nn = 0; nn < 4; ++nn)
          acc[mm][nn] = MFMA16(af[mm], bf[nn], acc[mm][nn]);
    }
    __syncthreads();
  }
  #pragma unroll
  for (int mm = 0; mm < 4; ++mm)
    #pragma unroll
    for (int nn = 0; nn < 4; ++nn){
      int j = n0 + wn * 64 + nn * 16 + arow;
      int h = j >> 6, dh = j & 63;
      float bval = bias[j];
      #pragma unroll
      for (int i = 0; i < 4; ++i){
        int sg = m0 + wm * 64 + mm * 16 + kg * 4 + i;
        int bb = sg >> 10, s = sg & 1023;
        float val = acc[mm][nn][i] + bval;
        size_t o = vtm ? (((size_t)((bb << 3) + h) * 64 + dh) * 1024 + s)
                       : (((size_t)((bb << 3) + h) * 1024 + s) * 64 + dh);
        out[o] = f2bf(val);
      }
    }
}

// ================= SPLIT PATH =================
// ---------------- kernel A v2: k-outer / q-inner dual-QK -> U, rsum -------------
// grid (16 b, 8 h, 4 qs) = 512 blocks; 1024 thr = 16 waves x 16 q-rows (256 rows/blk).
// Each K/K1 tile-pair (16 KB) staged ONCE serves all 256 rows (256 MFMA per staged
// tile vs 64 in R16's layout -> 4x fewer DMA events). Q frags live in regs all kernel.
__global__ void __launch_bounds__(1024)
k_qk(const u16* __restrict__ Qh, const u16* __restrict__ Kh,
     const u16* __restrict__ Q1h, const u16* __restrict__ K1h,
     const int* __restrict__ mask, u16* __restrict__ U, float* __restrict__ rsum)
{
  __shared__ __align__(16) u16 stg[2 * 8192];

  const int tid = threadIdx.x, lane = tid & 63, wid = tid >> 6;
  const int arow = lane & 15, kg = lane >> 4;
  const int b = blockIdx.x, h = blockIdx.y, qs = blockIdx.z;
  const size_t hb = (size_t)(b * 8 + h);

  // Q fragments: wave wid owns q-rows qs*256 + wid*16 .. +15
  const int qrow = qs * 256 + wid * 16 + arow;
  const u16* qp  = Qh  + (hb * 1024 + qrow) * 64 + kg * 8;
  const u16* q1p = Q1h + (hb * 1024 + qrow) * 64 + kg * 8;
  short8 aq0 = *(const short8*)qp,  aq1 = *(const short8*)(qp + 32);
  short8 ap0 = *(const short8*)q1p, ap1 = *(const short8*)(q1p + 32);

  // mask bits: bit t*4+cs = mask[col t*64 + cs*16 + arow]
  u64 mb = 0;
  #pragma unroll
  for (int t = 0; t < 16; ++t)
    #pragma unroll
    for (int cs = 0; cs < 4; ++cs)
      mb |= (mask[b * 1024 + t * 64 + cs * 16 + arow] != 0 ? 1ull : 0ull) << (t * 4 + cs);

  // staging map (16 KB tile-pair): half 0 = K1, half 1 = K
  const int ls_half = tid >> 9;
  const int ls_r = (tid & 511) >> 3;
  const int ls_c = (tid & 7) ^ (ls_r & 7);
  u16* const sbase = stg + wid * 512;
  const u16* lsrc = (ls_half ? Kh : K1h) + hb * 65536 + (size_t)ls_r * 64 + ls_c * 8;

  u16* const ubase = U + hb * 1048576;
  const int urow0 = qs * 256 + wid * 16 + kg * 4;   // +i

  gl_lds16(lsrc, sbase);
  __syncthreads();

  float sacc[4] = {0.f, 0.f, 0.f, 0.f};
  for (int t = 0; t < 16; ++t){
    if (t < 15)
      gl_lds16(lsrc + (size_t)(t + 1) * 4096, sbase + (((t + 1) & 1) << 13));
    const u16* kb = stg + ((t & 1) << 13);
    #pragma unroll
    for (int cs = 0; cs < 4; ++cs){
      const int krow = cs * 16 + arow;
      const int swl = (krow & 7) * 8;
      short8 b1a = *(const short8*)&kb[krow * 64 + ((     kg * 8) ^ swl)];
      short8 b1b = *(const short8*)&kb[krow * 64 + ((32 + kg * 8) ^ swl)];
      short8 bea = *(const short8*)&kb[4096 + krow * 64 + ((     kg * 8) ^ swl)];
      short8 beb = *(const short8*)&kb[4096 + krow * 64 + ((32 + kg * 8) ^ swl)];
      floatx4 cg4 = Z4, ce4 = Z4;
      cg4 = MFMA16(ap0, b1a, cg4); cg4 = MFMA16(ap1, b1b, cg4);
      ce4 = MFMA16(aq0, bea, ce4); ce4 = MFMA16(aq1, beb, ce4);
      const float msk = ((mb >> (t * 4 + cs)) & 1ull) ? 1.0f : 0.0f;
      #pragma unroll
      for (int i = 0; i < 4; ++i){
        float p = fexp2(ce4[i] * KEXP) * msk;
        float g = frcp(1.0f + fexp2(-cg4[i] * KEXP));
        sacc[i] += p;
        ubase[(size_t)(urow0 + i) * 1024 + t * 64 + cs * 16 + arow] = f2bf(p * g);
      }
    }
    __syncthreads();
  }

  #pragma unroll
  for (int i = 0; i < 4; ++i){
    #pragma unroll
    for (int off = 1; off <= 8; off <<= 1)
      sacc[i] += __shfl_xor(sacc[i], off, 64);
  }
  if (arow == 0){
    #pragma unroll
    for (int i = 0; i < 4; ++i)
      rsum[hb * 1024 + urow0 + i] = sacc[i];
  }
}

// ---------------- kernel B v3: r_att + PV from STAGED U; 4 blocks/CU -------------
// grid (16 b, 64 qt of 16 rows); 256 thr (4 waves); LDS 40960 B (dbuf x {U 4KB, V 16KB})
// -> 4 blocks/CU. Four independent DMA streams per CU raise the staging duty cycle
// that capped R16's 2-block version at 2.5 TB/s. V re-staged 2x more but L2-hot.
__global__ void __launch_bounds__(256)
__attribute__((amdgpu_waves_per_eu(4, 4)))
k_pvr(const u16* __restrict__ U, const float* __restrict__ rsum,
      const u16* __restrict__ Vt, u16* __restrict__ xa, float* __restrict__ ratt)
{
  extern __shared__ __align__(16) u16 stg2[];   // 2 bufs x 10240 u16: U[0,2048) V[2048,10240)

  const int tid = threadIdx.x, lane = tid & 63, wid = tid >> 6;   // wid 0..3
  const int arow = lane & 15, kg = lane >> 4;
  const int b = blockIdx.x, qt = blockIdx.y;    // 16 q-rows per block

  const int sr = tid >> 4;                      // staging row 0..15
  const int scs = (tid & 15) ^ (sr & 7);        // swizzled source chunk

  float racc[4][16];
  #pragma unroll
  for (int r = 0; r < 4; ++r)
    #pragma unroll
    for (int j = 0; j < 16; ++j) racc[r][j] = 0.f;

  for (int h = 0; h < 8; ++h){
    const size_t hb = (size_t)(b * 8 + h);
    const u16* ub = U  + hb * 1048576 + (size_t)(qt * 16) * 1024;
    const u16* vb = Vt + hb * 65536;

    float rlh[4], rlx[4];
    #pragma unroll
    for (int r = 0; r < 4; ++r)
      rlh[r] = frcp(rsum[hb * 1024 + qt * 16 + wid * 4 + r]) * 0.125f;
    #pragma unroll
    for (int i = 0; i < 4; ++i)
      rlx[i] = frcp(rsum[hb * 1024 + qt * 16 + kg * 4 + i]);

    // prologue: stage tile 0 -> buf 0
    gl_lds16(ub + (size_t)sr * 1024 + scs * 8, stg2 + tid * 8);
    #pragma unroll
    for (int q = 0; q < 4; ++q)
      gl_lds16(vb + (size_t)(q * 16 + sr) * 1024 + scs * 8,
               stg2 + 2048 + q * 2048 + tid * 8);
    __syncthreads();

    floatx4 cpv = Z4;
    for (int t = 0; t < 8; ++t){
      if (t < 7){
        const int nb = ((t + 1) & 1) * 10240;
        gl_lds16(ub + (size_t)sr * 1024 + (t + 1) * 128 + scs * 8, stg2 + nb + tid * 8);
        #pragma unroll
        for (int q = 0; q < 4; ++q)
          gl_lds16(vb + (size_t)(q * 16 + sr) * 1024 + (t + 1) * 128 + scs * 8,
                   stg2 + nb + 2048 + q * 2048 + tid * 8);
      }
      const u16* Ut  = stg2 + (t & 1) * 10240;
      const u16* Vts = Ut + 2048;
      // racc from staged U
      #pragma unroll
      for (int r = 0; r < 4; ++r){
        const int row = wid * 4 + r;
        u32 w = *(const u32*)&Ut[row * 128 + ((lane * 2) ^ ((row & 7) * 8))];
        racc[r][2 * t]     += __uint_as_float(w << 16) * rlh[r];
        racc[r][2 * t + 1] += __uint_as_float(w & 0xFFFF0000u) * rlh[r];
      }
      // PV MFMA from staged U + V (wave wid owns dh cols wid*16..+15)
      #pragma unroll
      for (int ks = 0; ks < 4; ++ks){
        short8 a  = *(const short8*)&Ut[arow * 128 + ((ks * 32 + kg * 8) ^ ((arow & 7) * 8))];
        short8 bv = *(const short8*)&Vts[(wid * 16 + arow) * 128 +
                                         ((ks * 32 + kg * 8) ^ ((arow & 7) * 8))];
        cpv = MFMA16(a, bv, cpv);
      }
      __syncthreads();
    }
    // epilogue: scale by 1/sum, write xa
    #pragma unroll
    for (int i = 0; i < 4; ++i){
      const int g = qt * 16 + kg * 4 + i;
      xa[((size_t)(b * 1024 + g)) * 512 + h * 64 + wid * 16 + arow] = f2bf(cpv[i] * rlx[i]);
    }
  }

  // r_att writeout (float2-coalesced: col = j*128 + lane*2 + par)
  #pragma unroll
  for (int r = 0; r < 4; ++r){
    const size_t rb = ((size_t)(b * 1024 + qt * 16 + wid * 4 + r)) * 1024;
    #pragma unroll
    for (int j = 0; j < 8; ++j){
      float2 v = {racc[r][2 * j], racc[r][2 * j + 1]};
      *(float2*)&ratt[rb + j * 128 + lane * 2] = v;
    }
  }
}

// ================= MONO FALLBACK (R6/R14-proven) =================
__global__ void __launch_bounds__(1024)
__attribute__((amdgpu_waves_per_eu(4, 4)))
k_attn(
    const u16* __restrict__ Qh, const u16* __restrict__ Kh, const u16* __restrict__ Vt,
    const u16* __restrict__ Q1h, const u16* __restrict__ K1h,
    const int* __restrict__ mask, u16* __restrict__ xa, float* __restrict__ ratt)
{
  extern __shared__ __align__(16) char smem[];
  u16* P   = (u16*)smem;
  u16* stg = (u16*)(smem + 131072);
  float* ssum = (float*)(smem + 131072);
  float* rls  = (float*)(smem + 131072 + 1024);

  const int tid = threadIdx.x, lane = tid & 63, wid = tid >> 6;
  const int arow = lane & 15, kg = lane >> 4;
  const int b = blockIdx.x, qt = blockIdx.y;
  const int r0 = (wid & 3) * 16;
  const int cres = ((wid >> 2) * 16) + arow;
  const int wrow = wid * 4;

  const int ls_half = tid >> 9;
  const int ls_r = (tid & 511) >> 3;
  const int ls_c = (tid & 7) ^ (ls_r & 7);
  const int pv_r = tid >> 4;
  const int pv_c = (tid & 15) ^ (pv_r & 7);
  u16* const sbase = stg + wid * 512;

  u32 mb = 0;
  #pragma unroll
  for (int t = 0; t < 16; ++t)
    mb |= (mask[b * 1024 + t * 64 + cres] != 0 ? 1u : 0u) << t;

  float racc[4][16];
  #pragma unroll
  for (int r = 0; r < 4; ++r)
    #pragma unroll
    for (int j = 0; j < 16; ++j) racc[r][j] = 0.f;

  for (int h = 0; h < 8; ++h){
    const size_t hb = (size_t)(b * 8 + h);
    const u16* qp  = Qh  + (hb * 1024 + qt * 64 + r0 + arow) * 64 + kg * 8;
    const u16* q1p = Q1h + (hb * 1024 + qt * 64 + r0 + arow) * 64 + kg * 8;
    short8 aq0 = *(const short8*)qp,  aq1 = *(const short8*)(qp + 32);
    short8 ap0 = *(const short8*)q1p, ap1 = *(const short8*)(q1p + 32);

    const u16* lsrc = (ls_half ? Kh : K1h) + hb * 65536 + (size_t)ls_r * 64 + ls_c * 8;

    gl_lds16(lsrc, sbase);
    __syncthreads();

    float sacc[4] = {0.f, 0.f, 0.f, 0.f};
    for (int t = 0; t < 16; ++t){
      if (t < 15)
        gl_lds16(lsrc + (size_t)(t + 1) * 4096, sbase + (((t + 1) & 1) << 13));
      const u16* kb = stg + ((t & 1) << 13);
      const int swl = (cres & 7) * 8;
      short8 b1a = *(const short8*)&kb[cres * 64 + ((     kg * 8) ^ swl)];
      short8 b1b = *(const short8*)&kb[cres * 64 + ((32 + kg * 8) ^ swl)];
      short8 bea = *(const short8*)&kb[4096 + cres * 64 + ((     kg * 8) ^ swl)];
      short8 beb = *(const short8*)&kb[4096 + cres * 64 + ((32 + kg * 8) ^ swl)];
      floatx4 cg = Z4, ce = Z4;
      cg = MFMA16(ap0, b1a, cg); cg = MFMA16(ap1, b1b, cg);
      ce = MFMA16(aq0, bea, ce); ce = MFMA16(aq1, beb, ce);
      const float msk = ((mb >> t) & 1u) ? 1.0f : 0.0f;
      #pragma unroll
      for (int i = 0; i < 4; ++i){
        float p = fexp2(ce[i] * KEXP) * msk;
        float g = frcp(1.0f + fexp2(-cg[i] * KEXP));
        sacc[i] += p;
        P[p_idx(r0 + kg * 4 + i, t * 64 + cres)] = f2bf(p * g);
      }
      __syncthreads();
    }

    #pragma unroll
    for (int i = 0; i < 4; ++i){
      #pragma unroll
      for (int off = 1; off <= 8; off <<= 1)
        sacc[i] += __shfl_xor(sacc[i], off, 64);
    }
    if (arow == 0){
      #pragma unroll
      for (int i = 0; i < 4; ++i)
        ssum[(r0 + kg * 4 + i) * 4 + (wid >> 2)] = sacc[i];
    }
    __syncthreads();

    #pragma unroll
    for (int r = 0; r < 4; ++r){
      const int row = wrow + r;
      float s = ssum[row * 4 + 0] + ssum[row * 4 + 1] + ssum[row * 4 + 2] + ssum[row * 4 + 3];
      float rl = frcp(s);
      if (lane == 0) rls[row] = rl;
      short8 u0 = *(const short8*)&P[p_idx(row, lane * 16)];
      short8 u1 = *(const short8*)&P[p_idx(row, lane * 16 + 8)];
      float rlh = rl * 0.125f;
      #pragma unroll
      for (int j = 0; j < 8; ++j){
        racc[r][j]     += __uint_as_float(((u32)(u16)u0[j]) << 16) * rlh;
        racc[r][8 + j] += __uint_as_float(((u32)(u16)u1[j]) << 16) * rlh;
      }
    }
    __syncthreads();
    float rlv[4];
    #pragma unroll
    for (int i = 0; i < 4; ++i) rlv[i] = rls[r0 + kg * 4 + i];
    __syncthreads();

    const u16* vsrc = Vt + hb * 65536 + (size_t)pv_r * 1024 + pv_c * 8;
    gl_lds16(vsrc, sbase);
    __syncthreads();

    floatx4 cpv = Z4;
    for (int t = 0; t < 8; ++t){
      if (t < 7)
        gl_lds16(vsrc + (size_t)(t + 1) * 128, sbase + (((t + 1) & 1) << 13));
      const u16* vb = stg + ((t & 1) << 13);
      const int swv = (cres & 7) * 8;
      #pragma unroll
      for (int ks = 0; ks < 4; ++ks){
        short8 a  = *(const short8*)&P[p_idx(r0 + arow, t * 128 + ks * 32 + kg * 8)];
        short8 bv = *(const short8*)&vb[cres * 128 + ((ks * 32 + kg * 8) ^ swv)];
        cpv = MFMA16(a, bv, cpv);
      }
      __syncthreads();
    }
    #pragma unroll
    for (int i = 0; i < 4; ++i)
      xa[((size_t)(b * 1024 + qt * 64 + r0 + kg * 4 + i)) * 512 + h * 64 + cres] =
          f2bf(cpv[i] * rlv[i]);
  }

  #pragma unroll
  for (int r = 0; r < 4; ++r){
    const size_t rb = ((size_t)(b * 1024 + qt * 64 + wrow + r)) * 1024 + lane * 16;
    #pragma unroll
    for (int q = 0; q < 4; ++q){
      float4 v = {racc[r][q * 4 + 0], racc[r][q * 4 + 1], racc[r][q * 4 + 2], racc[r][q * 4 + 3]};
      *(float4*)&ratt[rb + q * 4] = v;
    }
  }
}

// ---------------- final FC, 128x128 tile (R14-proven) ----------------
__global__ __launch_bounds__(256) void k_fc(
    const u16* __restrict__ xa, const u16* __restrict__ wt,
    const float* __restrict__ bias, float* __restrict__ out)
{
  __shared__ __align__(16) u16 Asf[128 * 64];
  __shared__ __align__(16) u16 Bsf[128 * 64];
  const int tid = threadIdx.x, lane = tid & 63, wid = tid >> 6;
  const int wm = wid >> 1, wn = wid & 1;
  const int m0 = blockIdx.x * 128, n0 = blockIdx.y * 128;
  const int arow = lane & 15, kg = lane >> 4;
  const int br = tid >> 3, bc = tid & 7;
  u16* const adst = Asf + wid * 512;
  u16* const bdst = Bsf + wid * 512;

  floatx4 acc[4][4];
  #pragma unroll
  for (int i = 0; i < 4; ++i)
    #pragma unroll
    for (int j = 0; j < 4; ++j) acc[i][j] = Z4;

  for (int k0 = 0; k0 < 512; k0 += 64){
    #pragma unroll
    for (int q = 0; q < 4; ++q){
      gl_lds16(xa + (size_t)(m0 + q * 32 + br) * 512 + k0 + ((bc ^ (br & 7)) * 8),
               adst + q * 2048);
      gl_lds16(wt + (size_t)(n0 + q * 32 + br) * 512 + k0 + ((bc ^ (br & 7)) * 8),
               bdst + q * 2048);
    }
    __syncthreads();
    #pragma unroll
    for (int kk = 0; kk < 2; ++kk){
      short8 af[4], bf[4];
      #pragma unroll
      for (int mm = 0; mm < 4; ++mm){
        int rr = wm * 64 + mm * 16 + arow;
        af[mm] = *(const short8*)&Asf[rr * 64 + ((kk * 32 + kg * 8) ^ ((rr & 7) * 8))];
      }
      #pragma unroll
      for (int nn = 0; nn < 4; ++nn){
        int rr = wn * 64 + nn * 16 + arow;
        bf[nn] = *(const short8*)&Bsf[rr * 64 + ((kk * 32 + kg * 8) ^ ((rr & 7) * 8))];
      }
      #pragma unroll
      for (int mm = 0; mm < 4; ++mm)
        #pragma unroll
        for (int nn = 0; nn < 4; ++nn)
          acc[mm][nn] = MFMA16(af[mm], bf[nn], acc[mm][nn]);
    }
    __syncthreads();
  }
  #pragma unroll
  for (int mm = 0; mm < 4; ++mm)
    #pragma unroll
    for (int nn = 0; nn < 4; ++nn){
      int j = n0 + wn * 64 + nn * 16 + arow;
      float bval = bias[j];
      #pragma unroll
      for (int i = 0; i < 4; ++i){
        int sg = m0 + wm * 64 + mm * 16 + kg * 4 + i;
        out[(size_t)sg * 512 + j] = acc[mm][nn][i] + bval;
      }
    }
}

extern "C" void kernel_launch(void* const* d_in, const int* in_sizes, int n_in,
                              void* d_out, int out_size, void* d_ws, size_t ws_size,
                              hipStream_t stream)
{
  const float* query = (const float*)d_in[0];
  const float* key   = (const float*)d_in[1];
  const float* value = (const float*)d_in[2];
  const int*   mask  = (const int*)d_in[3];
  const float* wq  = (const float*)d_in[4];  const float* bq  = (const float*)d_in[5];
  const float* wk  = (const float*)d_in[6];  const float* bk  = (const float*)d_in[7];
  const float* wv  = (const float*)d_in[8];  const float* bv  = (const float*)d_in[9];
  const float* wq1 = (const float*)d_in[10]; const float* bq1 = (const float*)d_in[11];
  const float* wk1 = (const float*)d_in[12]; const float* bk1 = (const float*)d_in[13];
  const float* wfc = (const float*)d_in[14]; const float* bfc = (const float*)d_in[15];

  u16* ws  = (u16*)d_ws;
  u16* Qh  = ws;
  u16* Kh  = Qh  + 8388608;
  u16* Vt  = Kh  + 8388608;
  u16* Q1h = Vt  + 8388608;
  u16* K1h = Q1h + 8388608;
  u16* xa  = K1h + 8388608;
  u16* wts = xa  + 8388608;           // 6 * 262144 u16
  u16* U   = wts + 6 * 262144;        // 134217728 u16 = 268 MB (split path only)
  float* rsum = (float*)(U + 134217728);  // 131072 f32

  const size_t need_split = (size_t)(51904512 + 134217728) * 2 + 524288;  // ~373 MB

  float* outx = (float*)d_out;
  float* ratt = outx + 8388608;

  k_wt6<<<dim3(1024, 6), dim3(256), 0, stream>>>(wq, wk, wv, wq1, wk1, wfc, wts);

  k_proj<<<dim3(128, 4, 5), dim3(256), 0, stream>>>(
      query, key, value, wts, bq, bk, bv, bq1, bk1, Qh, Kh, Vt, Q1h, K1h);

  if (ws_size >= need_split){
    (void)hipFuncSetAttribute((const void*)k_pvr,
                              hipFuncAttributeMaxDynamicSharedMemorySize, 40960);
    k_qk<<<dim3(16, 8, 4), dim3(1024), 0, stream>>>(
        Qh, Kh, Q1h, K1h, mask, U, rsum);
    k_pvr<<<dim3(16, 64), dim3(256), 40960, stream>>>(
        U, rsum, Vt, xa, ratt);
  } else {
    (void)hipFuncSetAttribute((const void*)k_attn,
                              hipFuncAttributeMaxDynamicSharedMemorySize, 163840);
    k_attn<<<dim3(16, 16), dim3(1024), 163840, stream>>>(
        Qh, Kh, Vt, Q1h, K1h, mask, xa, ratt);
  }

  k_fc<<<dim3(128, 4), dim3(256), 0, stream>>>(
      xa, wts + 5 * 262144, bfc, outx);
}